// Round 12
// baseline (799.104 us; speedup 1.0000x reference)
//
#include <hip/hip_runtime.h>
#include <hip/hip_bf16.h>
#include <math.h>

#define N_NODES 50000
#define N_EDGES 1600000
#define DIN 128
#define NH 4
#define D1 100
#define D2 20
#define NB 64
#define EPS_BN 1e-5f

// z1: HEAD-PARTITIONED [h][node][100] bf16 (10 MB/head) — agg1 blocks are
//     (4 dst x 1 head) with head = (blockIdx&7)>>1 so each XCD pair (round-
//     robin dispatch heuristic) gathers from one 10 MB slice -> L2-resident.
// z2: [node][80] bf16 unpadded; h1: [node][400] bf16 (feeds MFMA GEMM2)
// attention scores fused into GEMM epilogues; weights inline in agg kernels
// CSR rows sorted ascending -> bit-deterministic results every launch

typedef unsigned int uint;
typedef unsigned short ushort;
typedef short short8v __attribute__((ext_vector_type(8)));
typedef float float4v __attribute__((ext_vector_type(4)));

__device__ __forceinline__ void bf16x2_unpack(uint p, float& lo, float& hi) {
  lo = __uint_as_float(p << 16);
  hi = __uint_as_float(p & 0xffff0000u);
}

__device__ __forceinline__ ushort f2bf(float f) {  // RNE, finite inputs
  uint u = __float_as_uint(f);
  return (ushort)((u + 0x7fffu + ((u >> 16) & 1u)) >> 16);
}

// ---------------------------------------------------------------------------
// Prep both weight blocks in one launch.
// ---------------------------------------------------------------------------
__global__ void prep_b(const float* __restrict__ W1, const float* __restrict__ W2,
                       ushort* __restrict__ B1t, ushort* __restrict__ B2t) {
  int o = blockIdx.x * 256 + threadIdx.x;
  if (o < 65536) {
    int h = o >> 14;
    int r = o & 16383;
    int j = r >> 7, k = r & 127;
    float v = (j < D1) ? W1[((size_t)h * DIN + k) * D1 + j] : 0.f;
    B1t[o] = f2bf(v);
  } else {
    int idx = o - 65536;
    if (idx < 80 * 416) {
      int c = idx / 416, k = idx - c * 416;
      int h = c / D2, j = c - h * D2;
      float v = (k < NH * D1) ? W2[((size_t)h * (NH * D1) + k) * D2 + j] : 0.f;
      B2t[idx] = f2bf(v);
    }
  }
}

// ---------------------------------------------------------------------------
// GEMM1 via bf16 MFMA + fused scores. One head per block (64 rows x 128 cols).
// Output z1 head-partitioned: z1h[(h*N + row)*100 + col].
// ---------------------------------------------------------------------------
__global__ __launch_bounds__(256) void gemm1_mfma(const float* __restrict__ feat,
                                                  const ushort* __restrict__ B1t,
                                                  const float* __restrict__ a1,
                                                  ushort* __restrict__ z1h,
                                                  float* __restrict__ ssrc,
                                                  float* __restrict__ sdst) {
  __shared__ __align__(16) short As[64 * 136];
  __shared__ __align__(16) short Bs[128 * 136];
  const int row0 = blockIdx.x * 64;
  const int h = blockIdx.y;
  const int tid = threadIdx.x;
#pragma unroll
  for (int it = 0; it < 8; it++) {
    int idx = tid + it * 256;
    int r = idx >> 5, c4 = idx & 31;
    int row = row0 + r;
    float4 v = make_float4(0.f, 0.f, 0.f, 0.f);
    if (row < N_NODES) v = *reinterpret_cast<const float4*>(feat + (size_t)row * DIN + c4 * 4);
    short4 s;
    s.x = (short)f2bf(v.x); s.y = (short)f2bf(v.y);
    s.z = (short)f2bf(v.z); s.w = (short)f2bf(v.w);
    *reinterpret_cast<short4*>(&As[r * 136 + c4 * 4]) = s;
  }
  {
    const uint* bsrc = reinterpret_cast<const uint*>(B1t + (size_t)h * 16384);
#pragma unroll
    for (int it = 0; it < 32; it++) {
      int idx = tid + it * 256;
      int j = idx >> 6, kk = idx & 63;
      *reinterpret_cast<uint*>(&Bs[j * 136 + kk * 2]) = bsrc[idx];
    }
  }
  __syncthreads();
  const int wv = tid >> 6, lane = tid & 63;
  const int m = lane & 15, q = lane >> 4;
  float4v acc[8];
#pragma unroll
  for (int t = 0; t < 8; t++) acc[t] = (float4v){0.f, 0.f, 0.f, 0.f};
#pragma unroll
  for (int kq = 0; kq < 4; kq++) {
    short8v a = *reinterpret_cast<const short8v*>(&As[(wv * 16 + m) * 136 + kq * 32 + q * 8]);
#pragma unroll
    for (int t = 0; t < 8; t++) {
      short8v b = *reinterpret_cast<const short8v*>(&Bs[(t * 16 + m) * 136 + kq * 32 + q * 8]);
      acc[t] = __builtin_amdgcn_mfma_f32_16x16x32_bf16(a, b, acc[t], 0, 0, 0);
    }
  }
  // round + head-partitioned global store; keep bits for the LDS score tile
  ushort vals[8][4];
#pragma unroll
  for (int t = 0; t < 8; t++) {
    int cl = t * 16 + m;
#pragma unroll
    for (int reg = 0; reg < 4; reg++) {
      ushort v = f2bf(acc[t][reg]);
      vals[t][reg] = v;
      int row = row0 + wv * 16 + q * 4 + reg;
      if (cl < D1 && row < N_NODES)
        z1h[((size_t)h * N_NODES + row) * D1 + cl] = v;
    }
  }
  __syncthreads();  // all waves done reading Bs before reuse
#pragma unroll
  for (int t = 0; t < 8; t++) {
    int cl = t * 16 + m;
    if (cl < D1) {
#pragma unroll
      for (int reg = 0; reg < 4; reg++) {
        int lr = wv * 16 + q * 4 + reg;
        Bs[lr * 106 + cl] = (short)vals[t][reg];
      }
    }
  }
  __syncthreads();
  if (tid < 128) {
    int lr = tid >> 1, half = tid & 1;
    int grow = row0 + lr;
    if (grow < N_NODES) {
      const float* av = a1 + h * 2 * D1 + (half ? D1 : 0);
      const uint* tu = reinterpret_cast<const uint*>(Bs);
      float s = 0.f;
      for (int j = 0; j < D1 / 2; j++) {
        float lo, hi;
        bf16x2_unpack(tu[lr * 53 + j], lo, hi);
        s += lo * av[2 * j] + hi * av[2 * j + 1];
      }
      (half ? sdst : ssrc)[h * N_NODES + grow] = s;
    }
  }
}

// ---------------------------------------------------------------------------
// GEMM2 via bf16 MFMA + fused scores. 64 rows x 80 cols, 13 K-chunks.
// ---------------------------------------------------------------------------
__global__ __launch_bounds__(256) void gemm2_mfma(const ushort* __restrict__ h1b,
                                                  const ushort* __restrict__ B2t,
                                                  const float* __restrict__ a2,
                                                  ushort* __restrict__ z2b,
                                                  float* __restrict__ ssrc,
                                                  float* __restrict__ sdst) {
  __shared__ __align__(16) short As[64 * 40];
  __shared__ __align__(16) short Bs[80 * 40];
  __shared__ __align__(16) uint t2[64 * 41];
  const int row0 = blockIdx.x * 64;
  const int tid = threadIdx.x;
  const int wv = tid >> 6, lane = tid & 63;
  const int m = lane & 15, q = lane >> 4;
  const uint* au = reinterpret_cast<const uint*>(h1b);
  const uint* bu = reinterpret_cast<const uint*>(B2t);
  uint* asu = reinterpret_cast<uint*>(As);
  uint* bsu = reinterpret_cast<uint*>(Bs);
  float4v acc[5];
#pragma unroll
  for (int t = 0; t < 5; t++) acc[t] = (float4v){0.f, 0.f, 0.f, 0.f};
  for (int ch = 0; ch < 13; ch++) {
    int k0u = ch * 16;
    {
      int idx = tid;
#pragma unroll
      for (int it = 0; it < 4; it++, idx += 256) {
        int r = idx >> 4, ku = idx & 15;
        int row = row0 + r;
        uint v = 0;
        if (row < N_NODES && (k0u + ku) < 200) v = au[(size_t)row * 200 + k0u + ku];
        asu[r * 20 + ku] = v;
      }
      idx = tid;
#pragma unroll
      for (int it = 0; it < 5; it++, idx += 256) {
        int c = idx >> 4, ku = idx & 15;
        bsu[c * 20 + ku] = bu[(size_t)c * 208 + k0u + ku];
      }
    }
    __syncthreads();
    short8v a = *reinterpret_cast<const short8v*>(&As[(wv * 16 + m) * 40 + q * 8]);
#pragma unroll
    for (int t = 0; t < 5; t++) {
      short8v b = *reinterpret_cast<const short8v*>(&Bs[(t * 16 + m) * 40 + q * 8]);
      acc[t] = __builtin_amdgcn_mfma_f32_16x16x32_bf16(a, b, acc[t], 0, 0, 0);
    }
    __syncthreads();
  }
  short* t2s = reinterpret_cast<short*>(t2);
#pragma unroll
  for (int t = 0; t < 5; t++) {
    int col = t * 16 + m;
#pragma unroll
    for (int reg = 0; reg < 4; reg++) {
      int lr = wv * 16 + q * 4 + reg;
      int row = row0 + lr;
      ushort v = f2bf(acc[t][reg]);
      if (row < N_NODES) z2b[(size_t)row * (NH * D2) + col] = v;
      t2s[lr * 82 + col] = (short)v;
    }
  }
  __syncthreads();
  {
    int lr = tid >> 2, hh = tid & 3;
    int grow = row0 + lr;
    if (grow < N_NODES) {
      const float* as_ = a2 + hh * 2 * D2;
      const float* ad_ = as_ + D2;
      float s1 = 0.f, s2 = 0.f;
      for (int j = 0; j < D2 / 2; j++) {
        float lo, hi;
        bf16x2_unpack(t2[lr * 41 + hh * 10 + j], lo, hi);
        s1 += lo * as_[2 * j] + hi * as_[2 * j + 1];
        s2 += lo * ad_[2 * j] + hi * ad_[2 * j + 1];
      }
      ssrc[hh * N_NODES + grow] = s1;
      sdst[hh * N_NODES + grow] = s2;
    }
  }
}

// ---------------------------------------------------------------------------
// CSR build: histogram, 3-kernel hierarchical scan (+cursor), fill, row-sort
// ---------------------------------------------------------------------------
__global__ void hist_kernel(const int* __restrict__ dst, int* __restrict__ cnt) {
  int e = blockIdx.x * blockDim.x + threadIdx.x;
  if (e < N_EDGES) atomicAdd(&cnt[dst[e]], 1);
}

__global__ __launch_bounds__(512) void scan1_kernel(const int* __restrict__ cnt,
                                                    int* __restrict__ row_ptr,
                                                    int* __restrict__ btot, int n) {
  __shared__ int ws[8];
  int b = blockIdx.x, tid = threadIdx.x, lane = tid & 63, wv = tid >> 6;
  int i = b * 512 + tid;
  int v = (i < n) ? cnt[i] : 0;
  int orig = v;
  for (int off = 1; off < 64; off <<= 1) {
    int t = __shfl_up(v, off);
    if (lane >= off) v += t;
  }
  if (lane == 63) ws[wv] = v;
  __syncthreads();
  int wo = 0;
  for (int j = 0; j < wv; j++) wo += ws[j];
  if (i < n) row_ptr[i] = wo + v - orig;
  if (tid == 511) btot[b] = wo + v;
}

__global__ __launch_bounds__(128) void scan2_kernel(int* __restrict__ btot,
                                                    int* __restrict__ row_ptr_n, int nb) {
  __shared__ int ws2[2];
  int tid = threadIdx.x, lane = tid & 63, wv = tid >> 6;
  int v = (tid < nb) ? btot[tid] : 0;
  int orig = v;
  for (int off = 1; off < 64; off <<= 1) {
    int t = __shfl_up(v, off);
    if (lane >= off) v += t;
  }
  if (lane == 63) ws2[wv] = v;
  __syncthreads();
  int wo = (wv == 1) ? ws2[0] : 0;
  if (tid < nb) btot[tid] = wo + v - orig;
  if (tid == nb - 1) *row_ptr_n = wo + v;
}

__global__ __launch_bounds__(512) void scan3_kernel(int* __restrict__ row_ptr,
                                                    int* __restrict__ cursor,
                                                    const int* __restrict__ btot, int n) {
  int i = blockIdx.x * 512 + threadIdx.x;
  if (i < n) {
    int v = row_ptr[i] + btot[blockIdx.x];
    row_ptr[i] = v;
    cursor[i] = v;
  }
}

__global__ void fill_kernel(const int* __restrict__ src, const int* __restrict__ dst,
                            int* __restrict__ cursor, int* __restrict__ csr_src) {
  int e = blockIdx.x * blockDim.x + threadIdx.x;
  if (e < N_EDGES) {
    int p = atomicAdd(&cursor[dst[e]], 1);
    csr_src[p] = src[e];
  }
}

// Sort each dst row ascending (launch-invariant CSR despite atomic fill).
__global__ __launch_bounds__(256) void sortrows_kernel(const int* __restrict__ row_ptr,
                                                       int* __restrict__ csr) {
  __shared__ int buf[4][128];
  const int wave = threadIdx.x >> 6, lane = threadIdx.x & 63;
  const int d = blockIdx.x * 4 + wave;
  if (d >= N_NODES) return;
  const int beg = row_ptr[d];
  const int deg = row_ptr[d + 1] - beg;
  if (deg <= 1) return;
  if (deg <= 128) {
    for (int i = lane; i < 128; i += 64)
      buf[wave][i] = (i < deg) ? csr[beg + i] : 0x7fffffff;
    const int passes = deg + 1;
    for (int t = 0; t < passes; t++) {
      int i0 = 2 * lane + (t & 1);
      if (i0 + 1 < 128) {
        int a = buf[wave][i0], b = buf[wave][i0 + 1];
        if (a > b) { buf[wave][i0] = b; buf[wave][i0 + 1] = a; }
      }
    }
    for (int i = lane; i < deg; i += 64) csr[beg + i] = buf[wave][i];
  } else if (lane == 0) {
    for (int i = 1; i < deg; i++) {
      int key = csr[beg + i];
      int j = i - 1;
      while (j >= 0 && csr[beg + j] > key) { csr[beg + j + 1] = csr[beg + j]; j--; }
      csr[beg + j + 1] = key;
    }
  }
}

// ---------------------------------------------------------------------------
// GAT layer 1 aggregation, weights fused. Block = 4 dst x 1 head; head pinned
// by blockIdx&7 (XCD round-robin heuristic) so each XCD pair gathers from one
// 10 MB z1 head slice. Wave = one dst. Per 128-edge chunk: lane-parallel exp
// into per-wave LDS row (den inline), then 8-deep z-gather loop.
// ---------------------------------------------------------------------------
__global__ __launch_bounds__(256) void agg1_kernel(const ushort* __restrict__ z1h,
                                                   const float* __restrict__ ssrc,
                                                   const float* __restrict__ sdst,
                                                   const int* __restrict__ row_ptr,
                                                   const int* __restrict__ csr_src,
                                                   ushort* __restrict__ h1b) {
  __shared__ float lw[NH][128];
  const int slot = blockIdx.x & 7;
  const int h = slot >> 1;
  const int dg = (blockIdx.x >> 3) * 2 + (slot & 1);  // dst group [0,12500)
  const int wave = threadIdx.x >> 6, lane = threadIdx.x & 63;
  const int d = dg * 4 + wave;                         // < 50000 (12500*4)
  const int beg = row_ptr[d], end = row_ptr[d + 1];
  const int deg = end - beg;
  uint* h1u = reinterpret_cast<uint*>(h1b);
  const size_t ou = (size_t)d * 200 + h * 50 + lane;
  const bool act = lane < D1 / 2;  // 50 lanes
  if (deg == 0) {
    if (act) h1u[ou] = 0u;
    return;
  }
  const int hN = h * N_NODES;
  const float sd = sdst[hN + d];
  const uint* zb = reinterpret_cast<const uint*>(z1h) + (size_t)hN * 50;
  float den = 0.f;
  float aE0 = 0.f, aE1 = 0.f, aE2 = 0.f, aE3 = 0.f;
  float aO0 = 0.f, aO1 = 0.f, aO2 = 0.f, aO3 = 0.f;
  for (int c0 = 0; c0 < deg; c0 += 128) {
    const int cn = min(128, deg - c0);
    const int cb = beg + c0;
    for (int i = lane; i < cn; i += 64) {
      int s = csr_src[cb + i];
      float e = ssrc[hN + s] + sd;
      e = fmaxf(e, 0.01f * e);
      float x = __expf(e);
      lw[wave][i] = x;
      den += x;
    }
    if (act) {
      int j = 0;
      for (; j + 8 <= cn; j += 8) {
        int s0 = csr_src[cb + j + 0], s1 = csr_src[cb + j + 1];
        int s2 = csr_src[cb + j + 2], s3 = csr_src[cb + j + 3];
        int s4 = csr_src[cb + j + 4], s5 = csr_src[cb + j + 5];
        int s6 = csr_src[cb + j + 6], s7 = csr_src[cb + j + 7];
        float x0 = lw[wave][j + 0], x1 = lw[wave][j + 1];
        float x2 = lw[wave][j + 2], x3 = lw[wave][j + 3];
        float x4 = lw[wave][j + 4], x5 = lw[wave][j + 5];
        float x6 = lw[wave][j + 6], x7 = lw[wave][j + 7];
        uint p0 = zb[(size_t)s0 * 50 + lane];
        uint p1 = zb[(size_t)s1 * 50 + lane];
        uint p2 = zb[(size_t)s2 * 50 + lane];
        uint p3 = zb[(size_t)s3 * 50 + lane];
        uint p4 = zb[(size_t)s4 * 50 + lane];
        uint p5 = zb[(size_t)s5 * 50 + lane];
        uint p6 = zb[(size_t)s6 * 50 + lane];
        uint p7 = zb[(size_t)s7 * 50 + lane];
        float lo, hi;
        bf16x2_unpack(p0, lo, hi); aE0 += x0 * lo; aO0 += x0 * hi;
        bf16x2_unpack(p1, lo, hi); aE1 += x1 * lo; aO1 += x1 * hi;
        bf16x2_unpack(p2, lo, hi); aE2 += x2 * lo; aO2 += x2 * hi;
        bf16x2_unpack(p3, lo, hi); aE3 += x3 * lo; aO3 += x3 * hi;
        bf16x2_unpack(p4, lo, hi); aE0 += x4 * lo; aO0 += x4 * hi;
        bf16x2_unpack(p5, lo, hi); aE1 += x5 * lo; aO1 += x5 * hi;
        bf16x2_unpack(p6, lo, hi); aE2 += x6 * lo; aO2 += x6 * hi;
        bf16x2_unpack(p7, lo, hi); aE3 += x7 * lo; aO3 += x7 * hi;
      }
      for (; j < cn; j++) {
        int s = csr_src[cb + j];
        float x = lw[wave][j];
        uint p = zb[(size_t)s * 50 + lane];
        float lo, hi;
        bf16x2_unpack(p, lo, hi);
        aE0 += x * lo;
        aO0 += x * hi;
      }
    }
  }
#pragma unroll
  for (int off = 32; off > 0; off >>= 1) den += __shfl_xor(den, off);
  if (!act) return;
  float inv = 1.0f / den;
  float vE = ((aE0 + aE1) + (aE2 + aE3)) * inv;
  float vO = ((aO0 + aO1) + (aO2 + aO3)) * inv;
  vE = vE > 0.f ? vE : 0.f;
  vO = vO > 0.f ? vO : 0.f;
  h1u[ou] = (uint)f2bf(vE) | ((uint)f2bf(vO) << 16);
}

// ---------------------------------------------------------------------------
// GAT layer 2 aggregation, weights fused, + head-mean + relu (unchanged).
// ---------------------------------------------------------------------------
__global__ __launch_bounds__(256) void agg2_kernel(const ushort* __restrict__ z,
                                                   const float* __restrict__ ssrc,
                                                   const float* __restrict__ sdst,
                                                   const int* __restrict__ row_ptr,
                                                   const int* __restrict__ csr_src,
                                                   float* __restrict__ h2) {
  __shared__ float lw[NH][128];
  __shared__ float hbuf[NH][D2];
  const int d = blockIdx.x;
  const int h = threadIdx.x >> 6, lane = threadIdx.x & 63;
  const int beg = row_ptr[d], end = row_ptr[d + 1];
  const int deg = end - beg;
  const int g = lane / 10;
  const int j = lane - g * 10;
  if (deg > 0) {
    const int hN = h * N_NODES;
    const float sd = sdst[hN + d];
    const uint* zb = reinterpret_cast<const uint*>(z);
    const int hco = h * 10 + j;
    float den = 0.f, aE = 0.f, aO = 0.f;
    for (int c0 = 0; c0 < deg; c0 += 128) {
      const int cn = min(128, deg - c0);
      const int cb = beg + c0;
      for (int i = lane; i < cn; i += 64) {
        int s = csr_src[cb + i];
        float e = ssrc[hN + s] + sd;
        e = fmaxf(e, 0.01f * e);
        float x = __expf(e);
        lw[h][i] = x;
        den += x;
      }
      if (g < 6) {
        int i = g;
        for (; i + 6 < cn; i += 12) {
          int s0 = csr_src[cb + i];
          int s1 = csr_src[cb + i + 6];
          float x0 = lw[h][i];
          float x1 = lw[h][i + 6];
          uint p0 = zb[(size_t)s0 * 40 + hco];
          uint p1 = zb[(size_t)s1 * 40 + hco];
          float lo, hi;
          bf16x2_unpack(p0, lo, hi); aE += x0 * lo; aO += x0 * hi;
          bf16x2_unpack(p1, lo, hi); aE += x1 * lo; aO += x1 * hi;
        }
        if (i < cn) {
          int s = csr_src[cb + i];
          float x = lw[h][i];
          uint p = zb[(size_t)s * 40 + hco];
          float lo, hi;
          bf16x2_unpack(p, lo, hi);
          aE += x * lo;
          aO += x * hi;
        }
      }
    }
#pragma unroll
    for (int off = 32; off > 0; off >>= 1) den += __shfl_xor(den, off);
    float tE = aE, tO = aO;
#pragma unroll
    for (int k = 1; k < 6; k++) {
      tE += __shfl(aE, lane + 10 * k);
      tO += __shfl(aO, lane + 10 * k);
    }
    if (lane < 10) {
      float invd = 1.0f / den;
      hbuf[h][2 * j] = tE * invd;
      hbuf[h][2 * j + 1] = tO * invd;
    }
  } else {
    if (lane < 10) {
      hbuf[h][2 * j] = 0.f;
      hbuf[h][2 * j + 1] = 0.f;
    }
  }
  __syncthreads();
  if (threadIdx.x < D2) {
    int c = threadIdx.x;
    float m = 0.25f * (hbuf[0][c] + hbuf[1][c] + hbuf[2][c] + hbuf[3][c]);
    h2[(size_t)d * D2 + c] = m > 0.f ? m : 0.f;
  }
}

// ---------------------------------------------------------------------------
// Graph mean-pool: wave-level pre-reduction (graph_id is sorted).
// ---------------------------------------------------------------------------
__global__ __launch_bounds__(256) void pool_kernel(const float* __restrict__ h2,
                                                   const int* __restrict__ gid,
                                                   float* __restrict__ hg,
                                                   int* __restrict__ gcnt) {
  int wave = threadIdx.x >> 6, lane = threadIdx.x & 63;
  int n = (blockIdx.x * 4 + wave) * 64 + lane;
  bool valid = n < N_NODES;
  int g = gid[valid ? n : (N_NODES - 1)];
  int g0 = __shfl(g, 0), g63 = __shfl(g, 63);
  unsigned long long mask = __ballot(valid);
  if (g0 == g63) {
    if (lane == 0) atomicAdd(&gcnt[g0], (int)__popcll(mask));
#pragma unroll
    for (int c = 0; c < D2; c++) {
      float v = valid ? h2[(size_t)n * D2 + c] : 0.f;
#pragma unroll
      for (int off = 32; off > 0; off >>= 1) v += __shfl_xor(v, off);
      if (lane == 0) atomicAdd(&hg[g0 * D2 + c], v);
    }
  } else if (valid) {
    atomicAdd(&gcnt[g], 1);
    for (int c = 0; c < D2; c++) atomicAdd(&hg[g * D2 + c], h2[(size_t)n * D2 + c]);
  }
}

// ---------------------------------------------------------------------------
// Readout MLP + BatchNorm + final projection in one block.
// ---------------------------------------------------------------------------
__global__ __launch_bounds__(256) void head_kernel(const float* __restrict__ hg,
                                                   const int* __restrict__ gcnt,
                                                   const float* __restrict__ Wf1,
                                                   const float* __restrict__ bf1,
                                                   const float* __restrict__ Wf2,
                                                   const float* __restrict__ bf2,
                                                   const float* __restrict__ Wf3,
                                                   const float* __restrict__ bf3,
                                                   const float* __restrict__ gamma,
                                                   const float* __restrict__ beta,
                                                   float* __restrict__ out) {
  __shared__ float X[NB][D2];
  __shared__ float T1[NB][128];
  __shared__ float T2[NB][32];
  __shared__ float scale_s[32], shift_s[32];
  int tid = threadIdx.x;
  for (int i = tid; i < NB * D2; i += 256) {
    int r = i / D2, c = i % D2;
    X[r][c] = hg[i] / (float)gcnt[r];
  }
  __syncthreads();
  for (int i = tid; i < NB * 128; i += 256) {
    int r = i >> 7, c = i & 127;
    float s = bf1[c];
#pragma unroll
    for (int k = 0; k < D2; k++) s += X[r][k] * Wf1[k * 128 + c];
    T1[r][c] = s > 0.f ? s : 0.f;
  }
  __syncthreads();
  for (int i = tid; i < NB * 32; i += 256) {
    int r = i >> 5, c = i & 31;
    float s = bf2[c];
#pragma unroll
    for (int k = 0; k < 128; k++) s += T1[r][k] * Wf2[k * 32 + c];
    T2[r][c] = s;
  }
  __syncthreads();
  if (tid < 32) {
    float mu = 0.f;
    for (int r = 0; r < NB; r++) mu += T2[r][tid];
    mu *= (1.f / NB);
    float var = 0.f;
    for (int r = 0; r < NB; r++) {
      float dv = T2[r][tid] - mu;
      var += dv * dv;
    }
    var *= (1.f / NB);
    float sc = gamma[tid] * rsqrtf(var + EPS_BN);
    scale_s[tid] = sc;
    shift_s[tid] = beta[tid] - mu * sc;
  }
  __syncthreads();
  if (tid < NB) {
    float s = bf3[0];
#pragma unroll
    for (int c = 0; c < 32; c++) {
      float y = scale_s[c] * T2[tid][c] + shift_s[c];
      y = y > 0.f ? y : 0.f;
      s += y * Wf3[c];
    }
    out[tid] = s;
  }
}

// ---------------------------------------------------------------------------

extern "C" void kernel_launch(void* const* d_in, const int* in_sizes, int n_in,
                              void* d_out, int out_size, void* d_ws, size_t ws_size,
                              hipStream_t stream) {
  const float* feat = (const float*)d_in[0];
  const int* src = (const int*)d_in[1];
  const int* dst = (const int*)d_in[2];
  const int* gid = (const int*)d_in[3];
  const float* W1 = (const float*)d_in[4];
  const float* a1 = (const float*)d_in[5];
  const float* W2 = (const float*)d_in[6];
  const float* a2 = (const float*)d_in[7];
  const float* Wf1 = (const float*)d_in[8];
  const float* bf1 = (const float*)d_in[9];
  const float* Wf2 = (const float*)d_in[10];
  const float* bf2 = (const float*)d_in[11];
  const float* Wf3 = (const float*)d_in[12];
  const float* bf3 = (const float*)d_in[13];
  const float* gamma2 = (const float*)d_in[14];
  const float* beta2 = (const float*)d_in[15];
  float* outp = (float*)d_out;

  char* p = (char*)d_ws;
  auto alloc = [&](size_t bytes) {
    void* q = (void*)p;
    p += (bytes + 255) & ~(size_t)255;
    return q;
  };
  ushort* z1h = (ushort*)alloc((size_t)NH * N_NODES * D1 * 2);   // 40 MB head-partitioned
  ushort* z2b = (ushort*)alloc((size_t)N_NODES * NH * D2 * 2);   // 8 MB
  ushort* h1b = (ushort*)alloc((size_t)N_NODES * NH * D1 * 2);   // 40 MB
  float* h2 = (float*)alloc((size_t)N_NODES * D2 * 4);           // 4 MB
  float* ssrc = (float*)alloc((size_t)NH * N_NODES * 4);
  float* sdst = (float*)alloc((size_t)NH * N_NODES * 4);
  int* cnt = (int*)alloc((size_t)N_NODES * 4);
  int* row_ptr = (int*)alloc((size_t)(N_NODES + 1) * 4);
  int* cursor = (int*)alloc((size_t)N_NODES * 4);
  int* csr = (int*)alloc((size_t)N_EDGES * 4);
  int* btot = (int*)alloc((size_t)128 * 4);
  ushort* B1t = (ushort*)alloc((size_t)NH * 128 * 128 * 2);      // 128 KB
  ushort* B2t = (ushort*)alloc((size_t)80 * 416 * 2);            // 66.6 KB
  float* hg = (float*)alloc((size_t)NB * D2 * 4);
  int* gcnt = (int*)alloc((size_t)NB * 4);

  const int rows64 = (N_NODES + 63) / 64;        // 782
  const int eblk = (N_EDGES + 255) / 256;        // 6250
  const int nblk = (N_NODES + 255) / 256;        // 196
  const int sblk = (N_NODES + 511) / 512;        // 98
  const int srtblk = (N_NODES + 3) / 4;          // 12500
  const int a1blk = (N_NODES / 4 / 2) * 8;       // 50000: (bg<6250) x 8 slots

  // CSR build (+ deterministic row sort)
  hipMemsetAsync(cnt, 0, (size_t)N_NODES * 4, stream);
  hist_kernel<<<eblk, 256, 0, stream>>>(dst, cnt);
  scan1_kernel<<<sblk, 512, 0, stream>>>(cnt, row_ptr, btot, N_NODES);
  scan2_kernel<<<1, 128, 0, stream>>>(btot, row_ptr + N_NODES, sblk);
  scan3_kernel<<<sblk, 512, 0, stream>>>(row_ptr, cursor, btot, N_NODES);
  fill_kernel<<<eblk, 256, 0, stream>>>(src, dst, cursor, csr);
  sortrows_kernel<<<srtblk, 256, 0, stream>>>(row_ptr, csr);

  // Weight prep (single launch for both)
  prep_b<<<(65536 + 80 * 416 + 255) / 256, 256, 0, stream>>>(W1, W2, B1t, B2t);

  // Layer 1 (scores fused into GEMM epilogue; z1 head-partitioned)
  gemm1_mfma<<<dim3(rows64, NH), 256, 0, stream>>>(feat, B1t, a1, z1h, ssrc, sdst);
  agg1_kernel<<<a1blk, 256, 0, stream>>>(z1h, ssrc, sdst, row_ptr, csr, h1b);

  // Layer 2 (scores fused into GEMM epilogue)
  gemm2_mfma<<<rows64, 256, 0, stream>>>(h1b, B2t, a2, z2b, ssrc, sdst);
  agg2_kernel<<<N_NODES, 256, 0, stream>>>(z2b, ssrc, sdst, row_ptr, csr, h2);

  // Readout
  hipMemsetAsync(hg, 0, (size_t)NB * D2 * 4, stream);
  hipMemsetAsync(gcnt, 0, (size_t)NB * 4, stream);
  pool_kernel<<<nblk, 256, 0, stream>>>(h2, gid, hg, gcnt);
  head_kernel<<<1, 256, 0, stream>>>(hg, gcnt, Wf1, bf1, Wf2, bf2, Wf3, bf3,
                                     gamma2, beta2, outp);
}

// Round 13
// 782.356 us; speedup vs baseline: 1.0214x; 1.0214x over previous
//
#include <hip/hip_runtime.h>
#include <hip/hip_bf16.h>
#include <math.h>

#define N_NODES 50000
#define N_EDGES 1600000
#define DIN 128
#define NH 4
#define D1 100
#define D2 20
#define NB 64
#define EPS_BN 1e-5f

// z1: [node][400] bf16 unpadded; z2: [node][80] bf16 unpadded
// h1: [node][400] bf16 (feeds MFMA GEMM2 directly)
// attention scores fused into GEMM epilogues; weights inline in agg kernels
// CSR rows sorted ascending -> bit-deterministic results every launch
// agg2: full-row coalesced gather (1 wave-request/edge instead of 4)

typedef unsigned int uint;
typedef unsigned short ushort;
typedef short short8v __attribute__((ext_vector_type(8)));
typedef float float4v __attribute__((ext_vector_type(4)));

__device__ __forceinline__ void bf16x2_unpack(uint p, float& lo, float& hi) {
  lo = __uint_as_float(p << 16);
  hi = __uint_as_float(p & 0xffff0000u);
}

__device__ __forceinline__ ushort f2bf(float f) {  // RNE, finite inputs
  uint u = __float_as_uint(f);
  return (ushort)((u + 0x7fffu + ((u >> 16) & 1u)) >> 16);
}

// ---------------------------------------------------------------------------
// Prep both weight blocks in one launch.
// ---------------------------------------------------------------------------
__global__ void prep_b(const float* __restrict__ W1, const float* __restrict__ W2,
                       ushort* __restrict__ B1t, ushort* __restrict__ B2t) {
  int o = blockIdx.x * 256 + threadIdx.x;
  if (o < 65536) {
    int h = o >> 14;
    int r = o & 16383;
    int j = r >> 7, k = r & 127;
    float v = (j < D1) ? W1[((size_t)h * DIN + k) * D1 + j] : 0.f;
    B1t[o] = f2bf(v);
  } else {
    int idx = o - 65536;
    if (idx < 80 * 416) {
      int c = idx / 416, k = idx - c * 416;
      int h = c / D2, j = c - h * D2;
      float v = (k < NH * D1) ? W2[((size_t)h * (NH * D1) + k) * D2 + j] : 0.f;
      B2t[idx] = f2bf(v);
    }
  }
}

// ---------------------------------------------------------------------------
// GEMM1 via bf16 MFMA + fused scores. One head per block (64 rows x 128 cols).
// ---------------------------------------------------------------------------
__global__ __launch_bounds__(256) void gemm1_mfma(const float* __restrict__ feat,
                                                  const ushort* __restrict__ B1t,
                                                  const float* __restrict__ a1,
                                                  ushort* __restrict__ z1b,
                                                  float* __restrict__ ssrc,
                                                  float* __restrict__ sdst) {
  __shared__ __align__(16) short As[64 * 136];
  __shared__ __align__(16) short Bs[128 * 136];
  const int row0 = blockIdx.x * 64;
  const int h = blockIdx.y;
  const int tid = threadIdx.x;
#pragma unroll
  for (int it = 0; it < 8; it++) {
    int idx = tid + it * 256;
    int r = idx >> 5, c4 = idx & 31;
    int row = row0 + r;
    float4 v = make_float4(0.f, 0.f, 0.f, 0.f);
    if (row < N_NODES) v = *reinterpret_cast<const float4*>(feat + (size_t)row * DIN + c4 * 4);
    short4 s;
    s.x = (short)f2bf(v.x); s.y = (short)f2bf(v.y);
    s.z = (short)f2bf(v.z); s.w = (short)f2bf(v.w);
    *reinterpret_cast<short4*>(&As[r * 136 + c4 * 4]) = s;
  }
  {
    const uint* bsrc = reinterpret_cast<const uint*>(B1t + (size_t)h * 16384);
#pragma unroll
    for (int it = 0; it < 32; it++) {
      int idx = tid + it * 256;
      int j = idx >> 6, kk = idx & 63;
      *reinterpret_cast<uint*>(&Bs[j * 136 + kk * 2]) = bsrc[idx];
    }
  }
  __syncthreads();
  const int wv = tid >> 6, lane = tid & 63;
  const int m = lane & 15, q = lane >> 4;
  float4v acc[8];
#pragma unroll
  for (int t = 0; t < 8; t++) acc[t] = (float4v){0.f, 0.f, 0.f, 0.f};
#pragma unroll
  for (int kq = 0; kq < 4; kq++) {
    short8v a = *reinterpret_cast<const short8v*>(&As[(wv * 16 + m) * 136 + kq * 32 + q * 8]);
#pragma unroll
    for (int t = 0; t < 8; t++) {
      short8v b = *reinterpret_cast<const short8v*>(&Bs[(t * 16 + m) * 136 + kq * 32 + q * 8]);
      acc[t] = __builtin_amdgcn_mfma_f32_16x16x32_bf16(a, b, acc[t], 0, 0, 0);
    }
  }
  ushort vals[8][4];
#pragma unroll
  for (int t = 0; t < 8; t++) {
    int cl = t * 16 + m;
#pragma unroll
    for (int reg = 0; reg < 4; reg++) {
      ushort v = f2bf(acc[t][reg]);
      vals[t][reg] = v;
      int row = row0 + wv * 16 + q * 4 + reg;
      if (cl < D1 && row < N_NODES) z1b[(size_t)row * (NH * D1) + h * D1 + cl] = v;
    }
  }
  __syncthreads();  // all waves done reading Bs before reuse
#pragma unroll
  for (int t = 0; t < 8; t++) {
    int cl = t * 16 + m;
    if (cl < D1) {
#pragma unroll
      for (int reg = 0; reg < 4; reg++) {
        int lr = wv * 16 + q * 4 + reg;
        Bs[lr * 106 + cl] = (short)vals[t][reg];
      }
    }
  }
  __syncthreads();
  if (tid < 128) {
    int lr = tid >> 1, half = tid & 1;
    int grow = row0 + lr;
    if (grow < N_NODES) {
      const float* av = a1 + h * 2 * D1 + (half ? D1 : 0);
      const uint* tu = reinterpret_cast<const uint*>(Bs);
      float s = 0.f;
      for (int j = 0; j < D1 / 2; j++) {
        float lo, hi;
        bf16x2_unpack(tu[lr * 53 + j], lo, hi);
        s += lo * av[2 * j] + hi * av[2 * j + 1];
      }
      (half ? sdst : ssrc)[h * N_NODES + grow] = s;
    }
  }
}

// ---------------------------------------------------------------------------
// GEMM2 via bf16 MFMA + fused scores. 64 rows x 80 cols, 13 K-chunks.
// ---------------------------------------------------------------------------
__global__ __launch_bounds__(256) void gemm2_mfma(const ushort* __restrict__ h1b,
                                                  const ushort* __restrict__ B2t,
                                                  const float* __restrict__ a2,
                                                  ushort* __restrict__ z2b,
                                                  float* __restrict__ ssrc,
                                                  float* __restrict__ sdst) {
  __shared__ __align__(16) short As[64 * 40];
  __shared__ __align__(16) short Bs[80 * 40];
  __shared__ __align__(16) uint t2[64 * 41];
  const int row0 = blockIdx.x * 64;
  const int tid = threadIdx.x;
  const int wv = tid >> 6, lane = tid & 63;
  const int m = lane & 15, q = lane >> 4;
  const uint* au = reinterpret_cast<const uint*>(h1b);
  const uint* bu = reinterpret_cast<const uint*>(B2t);
  uint* asu = reinterpret_cast<uint*>(As);
  uint* bsu = reinterpret_cast<uint*>(Bs);
  float4v acc[5];
#pragma unroll
  for (int t = 0; t < 5; t++) acc[t] = (float4v){0.f, 0.f, 0.f, 0.f};
  for (int ch = 0; ch < 13; ch++) {
    int k0u = ch * 16;
    {
      int idx = tid;
#pragma unroll
      for (int it = 0; it < 4; it++, idx += 256) {
        int r = idx >> 4, ku = idx & 15;
        int row = row0 + r;
        uint v = 0;
        if (row < N_NODES && (k0u + ku) < 200) v = au[(size_t)row * 200 + k0u + ku];
        asu[r * 20 + ku] = v;
      }
      idx = tid;
#pragma unroll
      for (int it = 0; it < 5; it++, idx += 256) {
        int c = idx >> 4, ku = idx & 15;
        bsu[c * 20 + ku] = bu[(size_t)c * 208 + k0u + ku];
      }
    }
    __syncthreads();
    short8v a = *reinterpret_cast<const short8v*>(&As[(wv * 16 + m) * 40 + q * 8]);
#pragma unroll
    for (int t = 0; t < 5; t++) {
      short8v b = *reinterpret_cast<const short8v*>(&Bs[(t * 16 + m) * 40 + q * 8]);
      acc[t] = __builtin_amdgcn_mfma_f32_16x16x32_bf16(a, b, acc[t], 0, 0, 0);
    }
    __syncthreads();
  }
  short* t2s = reinterpret_cast<short*>(t2);
#pragma unroll
  for (int t = 0; t < 5; t++) {
    int col = t * 16 + m;
#pragma unroll
    for (int reg = 0; reg < 4; reg++) {
      int lr = wv * 16 + q * 4 + reg;
      int row = row0 + lr;
      ushort v = f2bf(acc[t][reg]);
      if (row < N_NODES) z2b[(size_t)row * (NH * D2) + col] = v;
      t2s[lr * 82 + col] = (short)v;
    }
  }
  __syncthreads();
  {
    int lr = tid >> 2, hh = tid & 3;
    int grow = row0 + lr;
    if (grow < N_NODES) {
      const float* as_ = a2 + hh * 2 * D2;
      const float* ad_ = as_ + D2;
      float s1 = 0.f, s2 = 0.f;
      for (int j = 0; j < D2 / 2; j++) {
        float lo, hi;
        bf16x2_unpack(t2[lr * 41 + hh * 10 + j], lo, hi);
        s1 += lo * as_[2 * j] + hi * as_[2 * j + 1];
        s2 += lo * ad_[2 * j] + hi * ad_[2 * j + 1];
      }
      ssrc[hh * N_NODES + grow] = s1;
      sdst[hh * N_NODES + grow] = s2;
    }
  }
}

// ---------------------------------------------------------------------------
// CSR build: histogram, 3-kernel hierarchical scan (+cursor), fill, row-sort
// ---------------------------------------------------------------------------
__global__ void hist_kernel(const int* __restrict__ dst, int* __restrict__ cnt) {
  int e = blockIdx.x * blockDim.x + threadIdx.x;
  if (e < N_EDGES) atomicAdd(&cnt[dst[e]], 1);
}

__global__ __launch_bounds__(512) void scan1_kernel(const int* __restrict__ cnt,
                                                    int* __restrict__ row_ptr,
                                                    int* __restrict__ btot, int n) {
  __shared__ int ws[8];
  int b = blockIdx.x, tid = threadIdx.x, lane = tid & 63, wv = tid >> 6;
  int i = b * 512 + tid;
  int v = (i < n) ? cnt[i] : 0;
  int orig = v;
  for (int off = 1; off < 64; off <<= 1) {
    int t = __shfl_up(v, off);
    if (lane >= off) v += t;
  }
  if (lane == 63) ws[wv] = v;
  __syncthreads();
  int wo = 0;
  for (int j = 0; j < wv; j++) wo += ws[j];
  if (i < n) row_ptr[i] = wo + v - orig;
  if (tid == 511) btot[b] = wo + v;
}

__global__ __launch_bounds__(128) void scan2_kernel(int* __restrict__ btot,
                                                    int* __restrict__ row_ptr_n, int nb) {
  __shared__ int ws2[2];
  int tid = threadIdx.x, lane = tid & 63, wv = tid >> 6;
  int v = (tid < nb) ? btot[tid] : 0;
  int orig = v;
  for (int off = 1; off < 64; off <<= 1) {
    int t = __shfl_up(v, off);
    if (lane >= off) v += t;
  }
  if (lane == 63) ws2[wv] = v;
  __syncthreads();
  int wo = (wv == 1) ? ws2[0] : 0;
  if (tid < nb) btot[tid] = wo + v - orig;
  if (tid == nb - 1) *row_ptr_n = wo + v;
}

__global__ __launch_bounds__(512) void scan3_kernel(int* __restrict__ row_ptr,
                                                    int* __restrict__ cursor,
                                                    const int* __restrict__ btot, int n) {
  int i = blockIdx.x * 512 + threadIdx.x;
  if (i < n) {
    int v = row_ptr[i] + btot[blockIdx.x];
    row_ptr[i] = v;
    cursor[i] = v;
  }
}

__global__ void fill_kernel(const int* __restrict__ src, const int* __restrict__ dst,
                            int* __restrict__ cursor, int* __restrict__ csr_src) {
  int e = blockIdx.x * blockDim.x + threadIdx.x;
  if (e < N_EDGES) {
    int p = atomicAdd(&cursor[dst[e]], 1);
    csr_src[p] = src[e];
  }
}

// Sort each dst row ascending (launch-invariant CSR despite atomic fill).
__global__ __launch_bounds__(256) void sortrows_kernel(const int* __restrict__ row_ptr,
                                                       int* __restrict__ csr) {
  __shared__ int buf[4][128];
  const int wave = threadIdx.x >> 6, lane = threadIdx.x & 63;
  const int d = blockIdx.x * 4 + wave;
  if (d >= N_NODES) return;
  const int beg = row_ptr[d];
  const int deg = row_ptr[d + 1] - beg;
  if (deg <= 1) return;
  if (deg <= 128) {
    for (int i = lane; i < 128; i += 64)
      buf[wave][i] = (i < deg) ? csr[beg + i] : 0x7fffffff;
    const int passes = deg + 1;
    for (int t = 0; t < passes; t++) {
      int i0 = 2 * lane + (t & 1);
      if (i0 + 1 < 128) {
        int a = buf[wave][i0], b = buf[wave][i0 + 1];
        if (a > b) { buf[wave][i0] = b; buf[wave][i0 + 1] = a; }
      }
    }
    for (int i = lane; i < deg; i += 64) csr[beg + i] = buf[wave][i];
  } else if (lane == 0) {
    for (int i = 1; i < deg; i++) {
      int key = csr[beg + i];
      int j = i - 1;
      while (j >= 0 && csr[beg + j] > key) { csr[beg + j + 1] = csr[beg + j]; j--; }
      csr[beg + j + 1] = key;
    }
  }
}

// ---------------------------------------------------------------------------
// GAT layer 1 aggregation, weights fused. Block = dst, wave = head (R11 —
// measured floor: ~197 us / 690 MB across five structural variants).
// ---------------------------------------------------------------------------
__global__ __launch_bounds__(256) void agg1_kernel(const ushort* __restrict__ z,
                                                   const float* __restrict__ ssrc,
                                                   const float* __restrict__ sdst,
                                                   const int* __restrict__ row_ptr,
                                                   const int* __restrict__ csr_src,
                                                   ushort* __restrict__ h1b) {
  __shared__ float lw[NH][128];
  const int d = blockIdx.x;
  const int h = threadIdx.x >> 6, lane = threadIdx.x & 63;
  const int beg = row_ptr[d], end = row_ptr[d + 1];
  const int deg = end - beg;
  uint* h1u = reinterpret_cast<uint*>(h1b);
  const size_t ou = (size_t)d * 200 + h * 50 + lane;
  const bool act = lane < D1 / 2;  // 50 lanes
  if (deg == 0) {
    if (act) h1u[ou] = 0u;
    return;
  }
  const int hN = h * N_NODES;
  const float sd = sdst[hN + d];
  const uint* zb = reinterpret_cast<const uint*>(z);
  const int hco = h * 50 + lane;
  float den = 0.f;
  float aE0 = 0.f, aE1 = 0.f, aE2 = 0.f, aE3 = 0.f;
  float aO0 = 0.f, aO1 = 0.f, aO2 = 0.f, aO3 = 0.f;
  for (int c0 = 0; c0 < deg; c0 += 128) {
    const int cn = min(128, deg - c0);
    const int cb = beg + c0;
    for (int i = lane; i < cn; i += 64) {
      int s = csr_src[cb + i];
      float e = ssrc[hN + s] + sd;
      e = fmaxf(e, 0.01f * e);
      float x = __expf(e);
      lw[h][i] = x;
      den += x;
    }
    if (act) {
      int j = 0;
      for (; j + 8 <= cn; j += 8) {
        int s0 = csr_src[cb + j + 0], s1 = csr_src[cb + j + 1];
        int s2 = csr_src[cb + j + 2], s3 = csr_src[cb + j + 3];
        int s4 = csr_src[cb + j + 4], s5 = csr_src[cb + j + 5];
        int s6 = csr_src[cb + j + 6], s7 = csr_src[cb + j + 7];
        float x0 = lw[h][j + 0], x1 = lw[h][j + 1];
        float x2 = lw[h][j + 2], x3 = lw[h][j + 3];
        float x4 = lw[h][j + 4], x5 = lw[h][j + 5];
        float x6 = lw[h][j + 6], x7 = lw[h][j + 7];
        uint p0 = zb[(size_t)s0 * 200 + hco];
        uint p1 = zb[(size_t)s1 * 200 + hco];
        uint p2 = zb[(size_t)s2 * 200 + hco];
        uint p3 = zb[(size_t)s3 * 200 + hco];
        uint p4 = zb[(size_t)s4 * 200 + hco];
        uint p5 = zb[(size_t)s5 * 200 + hco];
        uint p6 = zb[(size_t)s6 * 200 + hco];
        uint p7 = zb[(size_t)s7 * 200 + hco];
        float lo, hi;
        bf16x2_unpack(p0, lo, hi); aE0 += x0 * lo; aO0 += x0 * hi;
        bf16x2_unpack(p1, lo, hi); aE1 += x1 * lo; aO1 += x1 * hi;
        bf16x2_unpack(p2, lo, hi); aE2 += x2 * lo; aO2 += x2 * hi;
        bf16x2_unpack(p3, lo, hi); aE3 += x3 * lo; aO3 += x3 * hi;
        bf16x2_unpack(p4, lo, hi); aE0 += x4 * lo; aO0 += x4 * hi;
        bf16x2_unpack(p5, lo, hi); aE1 += x5 * lo; aO1 += x5 * hi;
        bf16x2_unpack(p6, lo, hi); aE2 += x6 * lo; aO2 += x6 * hi;
        bf16x2_unpack(p7, lo, hi); aE3 += x7 * lo; aO3 += x7 * hi;
      }
      for (; j < cn; j++) {
        int s = csr_src[cb + j];
        float x = lw[h][j];
        uint p = zb[(size_t)s * 200 + hco];
        float lo, hi;
        bf16x2_unpack(p, lo, hi);
        aE0 += x * lo;
        aO0 += x * hi;
      }
    }
  }
#pragma unroll
  for (int off = 32; off > 0; off >>= 1) den += __shfl_xor(den, off);
  if (!act) return;
  float inv = 1.0f / den;
  float vE = ((aE0 + aE1) + (aE2 + aE3)) * inv;
  float vO = ((aO0 + aO1) + (aO2 + aO3)) * inv;
  vE = vE > 0.f ? vE : 0.f;
  vO = vO > 0.f ? vO : 0.f;
  h1u[ou] = (uint)f2bf(vE) | ((uint)f2bf(vO) << 16);
}

// ---------------------------------------------------------------------------
// GAT layer 2 aggregation, weights fused, + head-mean + relu.
// Phase 1: wave w computes head-w weights for chunk into lw[w][] (den inline).
// Phase 2 (after barrier): wave w gathers FULL 160 B z2 rows for edges
// i === w (mod 4), coalesced across 40 lanes (lane = h*10+j -> uint lane of
// the row), 4-deep ILP. Cross-wave combine + head-mean via small LDS.
// ---------------------------------------------------------------------------
__global__ __launch_bounds__(256) void agg2_kernel(const ushort* __restrict__ z,
                                                   const float* __restrict__ ssrc,
                                                   const float* __restrict__ sdst,
                                                   const int* __restrict__ row_ptr,
                                                   const int* __restrict__ csr_src,
                                                   float* __restrict__ h2) {
  __shared__ float lw[NH][128];
  __shared__ float haccE[NH][40];
  __shared__ float haccO[NH][40];
  __shared__ float den_s[NH];
  __shared__ float outE[40], outO[40];
  const int d = blockIdx.x;
  const int w = threadIdx.x >> 6, lane = threadIdx.x & 63;
  const int beg = row_ptr[d], end = row_ptr[d + 1];
  const int deg = end - beg;
  if (deg == 0) {  // uniform per block
    if (threadIdx.x < D2 / 2)
      reinterpret_cast<float2*>(h2 + (size_t)d * D2)[threadIdx.x] = make_float2(0.f, 0.f);
    return;
  }
  const int hN = w * N_NODES;  // phase-1: this wave handles head w
  const float sd = sdst[hN + d];
  const uint* zb = reinterpret_cast<const uint*>(z);
  const int hl = lane / 10;    // phase-2: head owned by this lane (lane<40)
  const bool actl = lane < 40;
  float den = 0.f;
  float aE = 0.f, aO = 0.f;
  for (int c0 = 0; c0 < deg; c0 += 128) {
    const int cn = min(128, deg - c0);
    const int cb = beg + c0;
    // phase 1: head-w weights, lane-parallel
    for (int i = lane; i < cn; i += 64) {
      int s = csr_src[cb + i];
      float e = ssrc[hN + s] + sd;
      e = fmaxf(e, 0.01f * e);
      float x = __expf(e);
      lw[w][i] = x;
      den += x;
    }
    __syncthreads();
    // phase 2: full-row gathers, edges i === w (mod 4), 4-deep
    if (actl) {
      int i = w;
      for (; i + 12 < cn; i += 16) {
        int s0 = csr_src[cb + i], s1 = csr_src[cb + i + 4];
        int s2 = csr_src[cb + i + 8], s3 = csr_src[cb + i + 12];
        float x0 = lw[hl][i], x1 = lw[hl][i + 4];
        float x2 = lw[hl][i + 8], x3 = lw[hl][i + 12];
        uint p0 = zb[(size_t)s0 * 40 + lane];
        uint p1 = zb[(size_t)s1 * 40 + lane];
        uint p2 = zb[(size_t)s2 * 40 + lane];
        uint p3 = zb[(size_t)s3 * 40 + lane];
        float lo, hi;
        bf16x2_unpack(p0, lo, hi); aE += x0 * lo; aO += x0 * hi;
        bf16x2_unpack(p1, lo, hi); aE += x1 * lo; aO += x1 * hi;
        bf16x2_unpack(p2, lo, hi); aE += x2 * lo; aO += x2 * hi;
        bf16x2_unpack(p3, lo, hi); aE += x3 * lo; aO += x3 * hi;
      }
      for (; i < cn; i += 4) {
        int s = csr_src[cb + i];
        float x = lw[hl][i];
        uint p = zb[(size_t)s * 40 + lane];
        float lo, hi;
        bf16x2_unpack(p, lo, hi);
        aE += x * lo;
        aO += x * hi;
      }
    }
    __syncthreads();  // lw reused next chunk
  }
#pragma unroll
  for (int off = 32; off > 0; off >>= 1) den += __shfl_xor(den, off);
  if (lane == 0) den_s[w] = den;
  if (actl) { haccE[w][lane] = aE; haccO[w][lane] = aO; }
  __syncthreads();
  if (threadIdx.x < 40) {
    int l = threadIdx.x;
    float tE = haccE[0][l] + haccE[1][l] + haccE[2][l] + haccE[3][l];
    float tO = haccO[0][l] + haccO[1][l] + haccO[2][l] + haccO[3][l];
    float invd = 1.0f / den_s[l / 10];
    outE[l] = tE * invd;
    outO[l] = tO * invd;
  }
  __syncthreads();
  if (threadIdx.x < 10) {
    int j = threadIdx.x;
    float mE = 0.25f * (outE[j] + outE[10 + j] + outE[20 + j] + outE[30 + j]);
    float mO = 0.25f * (outO[j] + outO[10 + j] + outO[20 + j] + outO[30 + j]);
    mE = mE > 0.f ? mE : 0.f;
    mO = mO > 0.f ? mO : 0.f;
    reinterpret_cast<float2*>(h2 + (size_t)d * D2)[j] = make_float2(mE, mO);
  }
}

// ---------------------------------------------------------------------------
// Graph mean-pool: wave-level pre-reduction (graph_id is sorted).
// ---------------------------------------------------------------------------
__global__ __launch_bounds__(256) void pool_kernel(const float* __restrict__ h2,
                                                   const int* __restrict__ gid,
                                                   float* __restrict__ hg,
                                                   int* __restrict__ gcnt) {
  int wave = threadIdx.x >> 6, lane = threadIdx.x & 63;
  int n = (blockIdx.x * 4 + wave) * 64 + lane;
  bool valid = n < N_NODES;
  int g = gid[valid ? n : (N_NODES - 1)];
  int g0 = __shfl(g, 0), g63 = __shfl(g, 63);
  unsigned long long mask = __ballot(valid);
  if (g0 == g63) {
    if (lane == 0) atomicAdd(&gcnt[g0], (int)__popcll(mask));
#pragma unroll
    for (int c = 0; c < D2; c++) {
      float v = valid ? h2[(size_t)n * D2 + c] : 0.f;
#pragma unroll
      for (int off = 32; off > 0; off >>= 1) v += __shfl_xor(v, off);
      if (lane == 0) atomicAdd(&hg[g0 * D2 + c], v);
    }
  } else if (valid) {
    atomicAdd(&gcnt[g], 1);
    for (int c = 0; c < D2; c++) atomicAdd(&hg[g * D2 + c], h2[(size_t)n * D2 + c]);
  }
}

// ---------------------------------------------------------------------------
// Readout MLP + BatchNorm + final projection in one block.
// ---------------------------------------------------------------------------
__global__ __launch_bounds__(256) void head_kernel(const float* __restrict__ hg,
                                                   const int* __restrict__ gcnt,
                                                   const float* __restrict__ Wf1,
                                                   const float* __restrict__ bf1,
                                                   const float* __restrict__ Wf2,
                                                   const float* __restrict__ bf2,
                                                   const float* __restrict__ Wf3,
                                                   const float* __restrict__ bf3,
                                                   const float* __restrict__ gamma,
                                                   const float* __restrict__ beta,
                                                   float* __restrict__ out) {
  __shared__ float X[NB][D2];
  __shared__ float T1[NB][128];
  __shared__ float T2[NB][32];
  __shared__ float scale_s[32], shift_s[32];
  int tid = threadIdx.x;
  for (int i = tid; i < NB * D2; i += 256) {
    int r = i / D2, c = i % D2;
    X[r][c] = hg[i] / (float)gcnt[r];
  }
  __syncthreads();
  for (int i = tid; i < NB * 128; i += 256) {
    int r = i >> 7, c = i & 127;
    float s = bf1[c];
#pragma unroll
    for (int k = 0; k < D2; k++) s += X[r][k] * Wf1[k * 128 + c];
    T1[r][c] = s > 0.f ? s : 0.f;
  }
  __syncthreads();
  for (int i = tid; i < NB * 32; i += 256) {
    int r = i >> 5, c = i & 31;
    float s = bf2[c];
#pragma unroll
    for (int k = 0; k < 128; k++) s += T1[r][k] * Wf2[k * 32 + c];
    T2[r][c] = s;
  }
  __syncthreads();
  if (tid < 32) {
    float mu = 0.f;
    for (int r = 0; r < NB; r++) mu += T2[r][tid];
    mu *= (1.f / NB);
    float var = 0.f;
    for (int r = 0; r < NB; r++) {
      float dv = T2[r][tid] - mu;
      var += dv * dv;
    }
    var *= (1.f / NB);
    float sc = gamma[tid] * rsqrtf(var + EPS_BN);
    scale_s[tid] = sc;
    shift_s[tid] = beta[tid] - mu * sc;
  }
  __syncthreads();
  if (tid < NB) {
    float s = bf3[0];
#pragma unroll
    for (int c = 0; c < 32; c++) {
      float y = scale_s[c] * T2[tid][c] + shift_s[c];
      y = y > 0.f ? y : 0.f;
      s += y * Wf3[c];
    }
    out[tid] = s;
  }
}

// ---------------------------------------------------------------------------

extern "C" void kernel_launch(void* const* d_in, const int* in_sizes, int n_in,
                              void* d_out, int out_size, void* d_ws, size_t ws_size,
                              hipStream_t stream) {
  const float* feat = (const float*)d_in[0];
  const int* src = (const int*)d_in[1];
  const int* dst = (const int*)d_in[2];
  const int* gid = (const int*)d_in[3];
  const float* W1 = (const float*)d_in[4];
  const float* a1 = (const float*)d_in[5];
  const float* W2 = (const float*)d_in[6];
  const float* a2 = (const float*)d_in[7];
  const float* Wf1 = (const float*)d_in[8];
  const float* bf1 = (const float*)d_in[9];
  const float* Wf2 = (const float*)d_in[10];
  const float* bf2 = (const float*)d_in[11];
  const float* Wf3 = (const float*)d_in[12];
  const float* bf3 = (const float*)d_in[13];
  const float* gamma2 = (const float*)d_in[14];
  const float* beta2 = (const float*)d_in[15];
  float* outp = (float*)d_out;

  char* p = (char*)d_ws;
  auto alloc = [&](size_t bytes) {
    void* q = (void*)p;
    p += (bytes + 255) & ~(size_t)255;
    return q;
  };
  ushort* z1b = (ushort*)alloc((size_t)N_NODES * NH * D1 * 2);   // 40 MB
  ushort* z2b = (ushort*)alloc((size_t)N_NODES * NH * D2 * 2);   // 8 MB
  ushort* h1b = (ushort*)alloc((size_t)N_NODES * NH * D1 * 2);   // 40 MB
  float* h2 = (float*)alloc((size_t)N_NODES * D2 * 4);           // 4 MB
  float* ssrc = (float*)alloc((size_t)NH * N_NODES * 4);
  float* sdst = (float*)alloc((size_t)NH * N_NODES * 4);
  int* cnt = (int*)alloc((size_t)N_NODES * 4);
  int* row_ptr = (int*)alloc((size_t)(N_NODES + 1) * 4);
  int* cursor = (int*)alloc((size_t)N_NODES * 4);
  int* csr = (int*)alloc((size_t)N_EDGES * 4);
  int* btot = (int*)alloc((size_t)128 * 4);
  ushort* B1t = (ushort*)alloc((size_t)NH * 128 * 128 * 2);      // 128 KB
  ushort* B2t = (ushort*)alloc((size_t)80 * 416 * 2);            // 66.6 KB
  float* hg = (float*)alloc((size_t)NB * D2 * 4);
  int* gcnt = (int*)alloc((size_t)NB * 4);

  const int rows64 = (N_NODES + 63) / 64;        // 782
  const int eblk = (N_EDGES + 255) / 256;        // 6250
  const int nblk = (N_NODES + 255) / 256;        // 196
  const int sblk = (N_NODES + 511) / 512;        // 98
  const int srtblk = (N_NODES + 3) / 4;          // 12500

  // CSR build (+ deterministic row sort)
  hipMemsetAsync(cnt, 0, (size_t)N_NODES * 4, stream);
  hist_kernel<<<eblk, 256, 0, stream>>>(dst, cnt);
  scan1_kernel<<<sblk, 512, 0, stream>>>(cnt, row_ptr, btot, N_NODES);
  scan2_kernel<<<1, 128, 0, stream>>>(btot, row_ptr + N_NODES, sblk);
  scan3_kernel<<<sblk, 512, 0, stream>>>(row_ptr, cursor, btot, N_NODES);
  fill_kernel<<<eblk, 256, 0, stream>>>(src, dst, cursor, csr);
  sortrows_kernel<<<srtblk, 256, 0, stream>>>(row_ptr, csr);

  // Weight prep (single launch for both)
  prep_b<<<(65536 + 80 * 416 + 255) / 256, 256, 0, stream>>>(W1, W2, B1t, B2t);

  // Layer 1 (scores fused into GEMM epilogue)
  gemm1_mfma<<<dim3(rows64, NH), 256, 0, stream>>>(feat, B1t, a1, z1b, ssrc, sdst);
  agg1_kernel<<<N_NODES, 256, 0, stream>>>(z1b, ssrc, sdst, row_ptr, csr, h1b);

  // Layer 2 (scores fused into GEMM epilogue)
  gemm2_mfma<<<rows64, 256, 0, stream>>>(h1b, B2t, a2, z2b, ssrc, sdst);
  agg2_kernel<<<N_NODES, 256, 0, stream>>>(z2b, ssrc, sdst, row_ptr, csr, h2);

  // Readout
  hipMemsetAsync(hg, 0, (size_t)NB * D2 * 4, stream);
  hipMemsetAsync(gcnt, 0, (size_t)NB * 4, stream);
  pool_kernel<<<nblk, 256, 0, stream>>>(h2, gid, hg, gcnt);
  head_kernel<<<1, 256, 0, stream>>>(hg, gcnt, Wf1, bf1, Wf2, bf2, Wf3, bf3,
                                     gamma2, beta2, outp);
}